// Round 9
// baseline (1152.713 us; speedup 1.0000x reference)
//
#include <hip/hip_runtime.h>
#include <hip/hip_fp16.h>

#define N_NODES 260000
#define N_EDGES 8320000
#define H1 26
#define H2 11
#define GRAPH_NODES 26
#define N_GRAPHS 10000

#define NB 128            // nodes per bucket
#define NBUCK 2032        // ceil(260000/128)
#define NPB 256           // partition/count blocks
#define PBT 1024          // partition/count block threads
#define EPB 32500         // edges per partition block (256*32500 == 8,320,000)
#define ZS 16             // zmsg ushorts per node: 11 fp16 + fp16 deg + pad = 32 B
#define FSTRIDE 13        // facc LDS stride (coprime with 32 banks)
#define EREG 24           // register-stashed edges per thread (covers 6144/bucket)

// thirds of the node space (even boundaries; each third = 2.77 MB of zmsg)
#define TB1 86668u
#define TB2 173336u

#define NTL(p) __builtin_nontemporal_load(p)

// native clang vector types (HIP_vector_type is a class -> rejected by
// __builtin_nontemporal_* ; ext_vector_type is accepted)
typedef unsigned int u32x4 __attribute__((ext_vector_type(4)));
typedef unsigned int u32x2 __attribute__((ext_vector_type(2)));

__device__ __forceinline__ float2 up2(unsigned u) {
    __half2 h = *reinterpret_cast<const __half2*>(&u);
    return __half22float2(h);
}
__device__ __forceinline__ unsigned pk2(float a, float b) {
    __half2 h = __floats2half2_rn(a, b);
    return *reinterpret_cast<const unsigned*>(&h);
}

// ---- zero ghist + gpool ----
__global__ __launch_bounds__(256) void zero_kernel(unsigned* __restrict__ ghist,
                                                   float* __restrict__ gpool) {
    int i = blockIdx.x * 256 + threadIdx.x;
    if (i < NBUCK) ghist[i] = 0u;
    if (i < N_GRAPHS * 4) gpool[i] = 0.f;
}

// ---- count: bucket histogram via per-block LDS histograms ----
__global__ __launch_bounds__(PBT) void count_kernel(const int* __restrict__ col,
                                                    unsigned* __restrict__ ghist) {
    __shared__ unsigned lh[NBUCK];
    for (int b = threadIdx.x; b < NBUCK; b += PBT) lh[b] = 0u;
    __syncthreads();
    int e0 = blockIdx.x * EPB, e1 = e0 + EPB;
    for (int e = e0 + threadIdx.x; e < e1; e += PBT)
        atomicAdd(&lh[((unsigned)NTL(&col[e])) >> 7], 1u);
    __syncthreads();
    for (int b = threadIdx.x; b < NBUCK; b += PBT)
        if (lh[b]) atomicAdd(&ghist[b], lh[b]);
}

// ---- exclusive scan of 2032 bucket counts (single 1024-thread block) ----
__global__ __launch_bounds__(1024) void scan_kernel(const unsigned* __restrict__ ghist,
                                                    unsigned* __restrict__ bstart,
                                                    unsigned* __restrict__ bfill) {
    __shared__ unsigned v[2048];
    int t = threadIdx.x;
    int t1 = t + 1024;
    v[t]  = (t  < NBUCK) ? ghist[t]  : 0u;
    v[t1] = (t1 < NBUCK) ? ghist[t1] : 0u;
    __syncthreads();
    for (int off = 1; off < 2048; off <<= 1) {
        unsigned a0 = (t  >= off) ? v[t  - off] : 0u;
        unsigned a1 = (t1 >= off) ? v[t1 - off] : 0u;
        __syncthreads();
        v[t]  += a0;
        v[t1] += a1;
        __syncthreads();
    }
    if (t < NBUCK) {
        unsigned st = (t == 0) ? 0u : v[t - 1];
        bstart[t] = st; bfill[t] = st;
    }
    if (t1 < NBUCK) {
        unsigned st = v[t1 - 1];
        bstart[t1] = st; bfill[t1] = st;
        if (t1 == NBUCK - 1) bstart[NBUCK] = v[t1];
    }
}

// ---- partition: place packed (r<<7 | c&127) into bucket-grouped array ----
__global__ __launch_bounds__(PBT) void place_kernel(const int* __restrict__ row,
                                                    const int* __restrict__ col,
                                                    unsigned* __restrict__ bfill,
                                                    unsigned* __restrict__ part) {
    __shared__ unsigned lh[NBUCK];
    __shared__ unsigned lbase[NBUCK];
    for (int b = threadIdx.x; b < NBUCK; b += PBT) lh[b] = 0u;
    __syncthreads();
    int e0 = blockIdx.x * EPB, e1 = e0 + EPB;
    for (int e = e0 + threadIdx.x; e < e1; e += PBT)
        atomicAdd(&lh[((unsigned)NTL(&col[e])) >> 7], 1u);
    __syncthreads();
    for (int b = threadIdx.x; b < NBUCK; b += PBT) {
        unsigned c = lh[b];
        lbase[b] = c ? atomicAdd(&bfill[b], c) : 0u;
    }
    __syncthreads();
    for (int b = threadIdx.x; b < NBUCK; b += PBT) lh[b] = 0u;
    __syncthreads();
    for (int e = e0 + threadIdx.x; e < e1; e += PBT) {
        unsigned c = (unsigned)NTL(&col[e]);
        unsigned r = (unsigned)NTL(&row[e]);
        unsigned b = c >> 7;
        unsigned p = lbase[b] + atomicAdd(&lh[b], 1u);
        __builtin_nontemporal_store((r << 7) | (c & 127u), &part[p]);
    }
}

__device__ __forceinline__ void acc_node(float* acc, unsigned cl, float4 xv) {
    float* a = acc + cl * 5;
    atomicAdd(&a[0], xv.x); atomicAdd(&a[1], xv.y);
    atomicAdd(&a[2], xv.z); atomicAdd(&a[3], xv.w);
    atomicAdd(&a[4], 1.f);
}

// ---- layer 1 per bucket: LDS 4-dim sums + deg -> h1 -> z2' -> fp16 zmsg ----
// x (4.16 MB) stays L2-resident because part is streamed non-temporally.
__global__ __launch_bounds__(256) void layer1_kernel(const unsigned* __restrict__ part,
                                                     const unsigned* __restrict__ bstart,
                                                     const float* __restrict__ x,
                                                     const float* __restrict__ W1,
                                                     const float* __restrict__ b1,
                                                     const float* __restrict__ W2,
                                                     const float* __restrict__ b2,
                                                     ushort* __restrict__ zmsg) {
    __shared__ float acc[NB * 5];
    __shared__ float sW1[H1 * 4], sb1[H1], sW2[H2 * H1];
    for (int t = threadIdx.x; t < H1 * 4; t += 256) sW1[t] = W1[t];
    for (int t = threadIdx.x; t < H1; t += 256) sb1[t] = b1[t];
    for (int t = threadIdx.x; t < H2 * H1; t += 256) sW2[t] = W2[t];
    for (int t = threadIdx.x; t < NB * 5; t += 256) acc[t] = 0.f;
    __syncthreads();
    unsigned s = bstart[blockIdx.x], e = bstart[blockIdx.x + 1];
    unsigned i = s + threadIdx.x;
    for (; i + 256 < e; i += 512) {
        unsigned u1 = NTL(&part[i]), u2 = NTL(&part[i + 256]);
        unsigned r1 = u1 >> 7, cl1 = u1 & 127u;
        unsigned r2 = u2 >> 7, cl2 = u2 & 127u;
        float4 x1 = ((const float4*)x)[r1];
        float4 x2 = ((const float4*)x)[r2];
        acc_node(acc, cl1, x1);
        acc_node(acc, cl2, x2);
    }
    if (i < e) {
        unsigned u = NTL(&part[i]);
        acc_node(acc, u & 127u, ((const float4*)x)[u >> 7]);
    }
    __syncthreads();
    int base = blockIdx.x * NB;
    for (int n = threadIdx.x; n < NB; n += 256) {
        int node = base + n;
        if (node >= N_NODES) continue;
        float4 xv = ((const float4*)x)[node];      // self-loop
        float sx = acc[n*5+0] + xv.x, sy = acc[n*5+1] + xv.y;
        float sz = acc[n*5+2] + xv.z, sw = acc[n*5+3] + xv.w;
        float deg = acc[n*5+4] + 1.f;
        float h[H1];
        #pragma unroll
        for (int j = 0; j < H1; ++j)
            h[j] = tanhf(sb1[j] * deg + sx * sW1[j*4+0] + sy * sW1[j*4+1]
                                      + sz * sW1[j*4+2] + sw * sW1[j*4+3]);
        float z[H2];
        #pragma unroll
        for (int jj = 0; jj < H2; ++jj) {
            float v = 0.f;
            #pragma unroll
            for (int k = 0; k < H1; ++k) v += h[k] * sW2[jj*H1 + k];
            z[jj] = v;                             // z2' = W2 h1 (no bias)
        }
        u32x4 lo;
        u32x2 hi;
        lo.x = pk2(z[0], z[1]);  lo.y = pk2(z[2], z[3]);
        lo.z = pk2(z[4], z[5]);  lo.w = pk2(z[6], z[7]);
        hi.x = pk2(z[8], z[9]);  hi.y = pk2(z[10], deg);
        ushort* zp = zmsg + (size_t)node * ZS;
        __builtin_nontemporal_store(lo, (u32x4*)zp);
        __builtin_nontemporal_store(hi, (u32x2*)(zp + 8));
    }
}

__device__ __forceinline__ void acc_edge(float* facc, unsigned cl, u32x4 A, u32x2 B) {
    float* f = facc + cl * FSTRIDE;
    float2 v;
    v = up2(A.x); atomicAdd(&f[0], v.x); atomicAdd(&f[1], v.y);
    v = up2(A.y); atomicAdd(&f[2], v.x); atomicAdd(&f[3], v.y);
    v = up2(A.z); atomicAdd(&f[4], v.x); atomicAdd(&f[5], v.y);
    v = up2(A.w); atomicAdd(&f[6], v.x); atomicAdd(&f[7], v.y);
    v = up2(B.x); atomicAdd(&f[8], v.x); atomicAdd(&f[9], v.y);
    v = up2(B.y); atomicAdd(&f[10], v.x);
}

// ---- layer 2 per bucket: register-stash edges, 3 gather passes (each third of
// zmsg = 2.77 MB -> XCD-L2-resident), LDS accumulate; pool fused ----
__global__ __launch_bounds__(256) void layer2_kernel(const unsigned* __restrict__ part,
                                                     const unsigned* __restrict__ bstart,
                                                     const ushort* __restrict__ zmsg,
                                                     const float* __restrict__ b2,
                                                     float* __restrict__ gpool) {
    __shared__ float facc[NB * FSTRIDE];           // 6.7 KB
    __shared__ float sb2[H2];
    __shared__ float gacc[7][4];
    if (threadIdx.x < H2) sb2[threadIdx.x] = b2[threadIdx.x];
    if (threadIdx.x < 28) ((float*)gacc)[threadIdx.x] = 0.f;
    __syncthreads();
    int base = blockIdx.x * NB;
    // init: own-bucket rows (coalesced), self-loop + deg*b2
    for (int n = threadIdx.x; n < NB; n += 256) {
        const ushort* zp = zmsg + (size_t)(base + n) * ZS;
        u32x4 A = *(const u32x4*)zp;
        u32x2 B = *(const u32x2*)(zp + 8);
        float2 vd = up2(B.y);
        float deg = vd.y;
        float* f = facc + n * FSTRIDE;
        float2 v;
        v = up2(A.x); f[0] = v.x + deg*sb2[0]; f[1] = v.y + deg*sb2[1];
        v = up2(A.y); f[2] = v.x + deg*sb2[2]; f[3] = v.y + deg*sb2[3];
        v = up2(A.z); f[4] = v.x + deg*sb2[4]; f[5] = v.y + deg*sb2[5];
        v = up2(A.w); f[6] = v.x + deg*sb2[6]; f[7] = v.y + deg*sb2[7];
        v = up2(B.x); f[8] = v.x + deg*sb2[8]; f[9] = v.y + deg*sb2[9];
        f[10] = vd.x + deg*sb2[10];
    }
    __syncthreads();
    unsigned s = bstart[blockIdx.x], e = bstart[blockIdx.x + 1];
    // stash this thread's edges in registers (sentinel r = huge, never matches)
    unsigned ed[EREG];
    #pragma unroll
    for (int k = 0; k < EREG; ++k) {
        unsigned idx = s + threadIdx.x + (unsigned)k * 256u;
        ed[k] = (idx < e) ? NTL(&part[idx]) : 0xFFFFFFFFu;
    }
    // three passes; each pass's gather working set is one L2-resident third
    const unsigned lob[4] = {0u, TB1, TB2, (unsigned)N_NODES};
    #pragma unroll
    for (int ps = 0; ps < 3; ++ps) {
        unsigned lo = lob[ps], hi = lob[ps + 1];
        #pragma unroll
        for (int k = 0; k < EREG; ++k) {
            unsigned u = ed[k];
            unsigned r = u >> 7;
            if (r >= lo && r < hi) {
                unsigned cl = u & 127u;
                const ushort* p = zmsg + (size_t)r * ZS;
                u32x4 A = *(const u32x4*)p;
                u32x2 B = *(const u32x2*)(p + 8);
                acc_edge(facc, cl, A, B);
            }
        }
    }
    // safety tail (buckets > EREG*256 edges — statistically impossible, but correct)
    for (unsigned i = s + threadIdx.x + EREG * 256u; i < e; i += 256u) {
        unsigned u = part[i];
        unsigned r = u >> 7, cl = u & 127u;
        const ushort* p = zmsg + (size_t)r * ZS;
        u32x4 A = *(const u32x4*)p;
        u32x2 B = *(const u32x2*)(p + 8);
        acc_edge(facc, cl, A, B);
    }
    __syncthreads();
    // tanh + maxpool + per-graph partial sums (LDS), then few global atomics
    int gfirst = base / GRAPH_NODES;
    int lastnode = min(base + NB - 1, N_NODES - 1);
    int glast = lastnode / GRAPH_NODES;
    for (int n = threadIdx.x; n < NB; n += 256) {
        int node = base + n;
        if (node >= N_NODES) continue;
        const float* h = facc + n * FSTRIDE;
        float p0 = tanhf(fmaxf(h[0], h[1]));
        float p1 = tanhf(fmaxf(fmaxf(h[2], h[3]), h[4]));
        float p2 = tanhf(fmaxf(fmaxf(h[5], h[6]), h[7]));
        float p3 = tanhf(fmaxf(fmaxf(h[8], h[9]), h[10]));
        int lg = node / GRAPH_NODES - gfirst;
        atomicAdd(&gacc[lg][0], p0);
        atomicAdd(&gacc[lg][1], p1);
        atomicAdd(&gacc[lg][2], p2);
        atomicAdd(&gacc[lg][3], p3);
    }
    __syncthreads();
    int ng = glast - gfirst + 1;
    for (int t = threadIdx.x; t < ng * 4; t += 256) {
        int lg = t >> 2, c = t & 3;
        float v = gacc[lg][c];
        if (v != 0.f) atomicAdd(&gpool[(size_t)(gfirst + lg) * 4 + c], v);
    }
}

// ---- final: linear + softmax per graph ----
__global__ __launch_bounds__(256) void final_kernel(const float* __restrict__ gpool,
                                                    const float* __restrict__ Wl,
                                                    const float* __restrict__ bl,
                                                    float* __restrict__ out) {
    int g = blockIdx.x * 256 + threadIdx.x;
    if (g >= N_GRAPHS) return;
    float4 p = ((const float4*)gpool)[g];
    float o0 = bl[0] + p.x * Wl[0] + p.y * Wl[1] + p.z * Wl[2] + p.w * Wl[3];
    float o1 = bl[1] + p.x * Wl[4] + p.y * Wl[5] + p.z * Wl[6] + p.w * Wl[7];
    float m = fmaxf(o0, o1);
    float e0 = expf(o0 - m), e1 = expf(o1 - m);
    float s = e0 + e1;
    out[g * 2 + 0] = e0 / s;
    out[g * 2 + 1] = e1 / s;
}

extern "C" void kernel_launch(void* const* d_in, const int* in_sizes, int n_in,
                              void* d_out, int out_size, void* d_ws, size_t ws_size,
                              hipStream_t stream) {
    const float* x  = (const float*)d_in[0];
    const int* ei   = (const int*)d_in[1];
    const float* W1 = (const float*)d_in[2];
    const float* b1 = (const float*)d_in[3];
    const float* W2 = (const float*)d_in[4];
    const float* b2 = (const float*)d_in[5];
    const float* Wl = (const float*)d_in[6];
    const float* bl = (const float*)d_in[7];
    float* out = (float*)d_out;

    const int* row = ei;            // edge_index[0] (source)
    const int* col = ei + N_EDGES;  // edge_index[1] (destination)

    // ws layout: zmsg 8.32 MB (fp16 rows, 32 B/node) | part 33.3 MB |
    //            bstart/bfill/ghist ~24 KB | gpool 160 KB  => ~41.8 MB
    ushort*   zmsg   = (ushort*)d_ws;
    unsigned* part   = (unsigned*)((char*)d_ws + (size_t)NBUCK * NB * ZS * 2);
    unsigned* bstart = part + N_EDGES;
    unsigned* bfill  = bstart + NBUCK + 1;
    unsigned* ghist  = bfill + NBUCK;
    float*    gpool  = (float*)(ghist + NBUCK);

    zero_kernel<<<(N_GRAPHS*4 + 255)/256, 256, 0, stream>>>(ghist, gpool);
    count_kernel<<<NPB, PBT, 0, stream>>>(col, ghist);
    scan_kernel<<<1, 1024, 0, stream>>>(ghist, bstart, bfill);
    place_kernel<<<NPB, PBT, 0, stream>>>(row, col, bfill, part);
    layer1_kernel<<<NBUCK, 256, 0, stream>>>(part, bstart, x, W1, b1, W2, b2, zmsg);
    layer2_kernel<<<NBUCK, 256, 0, stream>>>(part, bstart, zmsg, b2, gpool);
    final_kernel<<<(N_GRAPHS + 255)/256, 256, 0, stream>>>(gpool, Wl, bl, out);
}